// Round 1
// 327.986 us; speedup vs baseline: 1.0845x; 1.0845x over previous
//
#include <hip/hip_runtime.h>
#include <hip/hip_bf16.h>

typedef unsigned short ushort_t;
typedef __attribute__((ext_vector_type(8))) short short8;
typedef __attribute__((ext_vector_type(8))) unsigned short ushort8;
typedef __attribute__((ext_vector_type(4))) float f32x4;

#define MFMA16(a,b,c) __builtin_amdgcn_mfma_f32_16x16x32_bf16((a),(b),(c),0,0,0)

__device__ __forceinline__ ushort_t f2bf(float f) {
  unsigned int u = __builtin_bit_cast(unsigned int, f);
  u += 0x7FFFu + ((u >> 16) & 1u);
  return (ushort_t)(u >> 16);
}
__device__ __forceinline__ unsigned int pack2bf(float a, float b) {
  unsigned int ua = __builtin_bit_cast(unsigned int, a);
  unsigned int ub = __builtin_bit_cast(unsigned int, b);
  ua += 0x7FFFu + ((ua >> 16) & 1u);
  ub += 0x7FFFu + ((ub >> 16) & 1u);
  return (ua >> 16) | (ub & 0xFFFF0000u);
}

// Problem dims
#define DMd 1024
#define DPd 128
#define PPd 256

// Workspace layout (ushort element offsets unless noted)
// KWqExt fragments: [chunk 8][ct 17][k4 4][lane 64][8]  (272 x 1024 bf16)
#define KWQ_OFF 0
#define KWQ_SIZE (8*17*4*512)          // 278528
// VWo fragments: [ctg 64][k8 8][lane 64][8]             (256 x 1024 bf16)
#define VWO_OFF KWQ_SIZE
#define VWO_SIZE (64*8*512)            // 262144
#define KV_BYTE_OFF ((size_t)(KWQ_SIZE + VWO_SIZE) * 2)  // 1,081,344 B; then k,v fp32

// ---------------------------------------------------------------------------
// prep1: k = prim @ Wk^T, v = prim @ Wv^T  (fp32, [256][128] each)
// ---------------------------------------------------------------------------
__global__ void prep1_kernel(const float* __restrict__ prim, const float* __restrict__ Wk,
                             const float* __restrict__ Wv, ushort_t* __restrict__ ws) {
  float* kf = (float*)((char*)ws + KV_BYTE_OFF);
  float* vf = kf + 32768;
  int idx = blockIdx.x * 256 + threadIdx.x;      // 65536 total
  int mat = idx >> 15, rem = idx & 32767;
  int p = rem >> 7, d = rem & 127;
  const float4* pr = (const float4*)(prim + p * 128);
  const float4* wr = (const float4*)((mat ? Wv : Wk) + d * 128);
  float s0 = 0.f, s1 = 0.f;
  #pragma unroll
  for (int j = 0; j < 32; j += 2) {
    float4 a = pr[j], b = wr[j];
    s0 += a.x*b.x + a.y*b.y + a.z*b.z + a.w*b.w;
    float4 a2 = pr[j+1], b2 = wr[j+1];
    s1 += a2.x*b2.x + a2.y*b2.y + a2.z*b2.z + a2.w*b2.w;
  }
  (mat ? vf : kf)[rem] = s0 + s1;
}

// ---------------------------------------------------------------------------
// prep2: blocks 0..67  -> KWqExt = k @ Wq (row 256 = gate_w, 257..271 = 0), frag-major
//        blocks 68..131 -> VWo = v @ Wo^T, frag-major
// ---------------------------------------------------------------------------
__global__ void prep2_kernel(const float* __restrict__ Wq, const float* __restrict__ Wo,
                             const float* __restrict__ gate_w, ushort_t* __restrict__ ws) {
  const float* kf = (const float*)((const char*)ws + KV_BYTE_OFF);
  const float* vf = kf + 32768;
  const int b = blockIdx.x, t = threadIdx.x;
  if (b < 68) {
    // p-tile (b>>2)*16, m-slice (b&3)*256; thread: p = p0 + t>>4, m = m0 + (t&15)*16 .. +16
    const int p  = (b >> 2) * 16 + (t >> 4);
    const int m0 = (b & 3) * 256 + (t & 15) * 16;
    float acc[16];
    #pragma unroll
    for (int j = 0; j < 16; ++j) acc[j] = 0.f;
    if (p < 256) {
      const float* kp = kf + p * 128;
      for (int d = 0; d < 128; ++d) {
        float kv = kp[d];
        const float4* wr = (const float4*)(Wq + (size_t)d * 1024 + m0);
        #pragma unroll
        for (int q = 0; q < 4; ++q) {
          float4 w = wr[q];
          acc[q*4+0] += kv * w.x; acc[q*4+1] += kv * w.y;
          acc[q*4+2] += kv * w.z; acc[q*4+3] += kv * w.w;
        }
      }
    } else if (p == 256) {
      #pragma unroll
      for (int j = 0; j < 16; ++j) acc[j] = gate_w[m0 + j];
    } // p>256 stays 0
    const int ct = p >> 4, l16p = p & 15;
    const int c = m0 >> 7, k4 = (m0 >> 5) & 3, q0 = (m0 >> 3) & 3;
    ushort8 u0, u1;
    #pragma unroll
    for (int j = 0; j < 8; ++j) { u0[j] = f2bf(acc[j]); u1[j] = f2bf(acc[8+j]); }
    size_t base = ((size_t)(c * 17 + ct) * 4 + k4) * 512;
    *(ushort8*)&ws[KWQ_OFF + base + (size_t)(q0 * 16 + l16p) * 8]       = u0;
    *(ushort8*)&ws[KWQ_OFF + base + (size_t)((q0 + 1) * 16 + l16p) * 8] = u1;
  } else {
    __shared__ float vs[16 * 128];
    const int bb = b - 68;
    const int p0 = (bb >> 2) * 16;
    const int m  = (bb & 3) * 256 + t;
    {
      int row = t >> 4, col = (t & 15) * 8;
      const float4* src = (const float4*)(vf + (p0 + row) * 128 + col);
      float4 a0 = src[0], a1 = src[1];
      *(float4*)&vs[row * 128 + col]     = a0;
      *(float4*)&vs[row * 128 + col + 4] = a1;
    }
    __syncthreads();
    float acc[16];
    #pragma unroll
    for (int j = 0; j < 16; ++j) acc[j] = 0.f;
    const float4* wr = (const float4*)(Wo + (size_t)m * 128);
    for (int d4 = 0; d4 < 32; ++d4) {
      float4 w = wr[d4];
      #pragma unroll
      for (int pp = 0; pp < 16; ++pp) {
        float4 v4 = *(const float4*)&vs[pp * 128 + d4 * 4];
        acc[pp] += w.x*v4.x + w.y*v4.y + w.z*v4.z + w.w*v4.w;
      }
    }
    const int ctg = m >> 4, l16m = m & 15;
    ushort8 u0, u1;
    #pragma unroll
    for (int j = 0; j < 8; ++j) { u0[j] = f2bf(acc[j]); u1[j] = f2bf(acc[8+j]); }
    const int pA = p0, pB = p0 + 8;
    *(ushort8*)&ws[VWO_OFF + ((size_t)(ctg*8 + (pA>>5))*512) + (size_t)(((pA>>3)&3)*16 + l16m)*8] = u0;
    *(ushort8*)&ws[VWO_OFF + ((size_t)(ctg*8 + (pB>>5))*512) + (size_t)(((pB>>3)&3)*16 + l16m)*8] = u1;
  }
}

// ---------------------------------------------------------------------------
// fused: per block 32 tokens (1024 blocks -> 4 blocks/CU, 16 waves/CU).
//   scores[32,272] = x_tile @ KWqExt^T  (ct-split across 4 waves, frag-major B)
//   cross-wave softmax (cols 0..255), gate from col 256, gate folded into slab
//   out[32,1024] = slab @ VWo  (wave w owns cols [w*256,+256)), NT stores
// x staging is double-buffered: 1 barrier per K-chunk, next chunk's global
// loads issued before current chunk's MFMAs.
// ---------------------------------------------------------------------------
#define LDX 136        // x-tile row stride, ushorts (128 + 8 pad)
#define LDSLAB 264     // attn slab row stride, ushorts (256 + 8 pad)

__global__ __launch_bounds__(256, 4) void fused_kernel(
    const float* __restrict__ x, const float* __restrict__ gate_b,
    const ushort_t* __restrict__ ws, float* __restrict__ out)
{
  // 2 xt buffers (2*32*136*2 = 17408 B); slab (32*264*2 = 16896 B) aliases them.
  __shared__ __align__(16) char smem[2 * 32 * LDX * 2 + 32 * 4 * 4 * 2 + 32 * 4];
  ushort_t* xt0      = (ushort_t*)smem;                       // [32][136]
  ushort_t* xt1      = xt0 + 32 * LDX;
  ushort_t* slab     = (ushort_t*)smem;                       // [32][264] (attn phase)
  float*    pmax     = (float*)(smem + 2 * 32 * LDX * 2);     // [32][4]
  float*    psum     = pmax + 128;                            // [32][4]
  float*    gate_lds = psum + 128;                            // [32]

  const int t = threadIdx.x, wid = t >> 6, lane = t & 63;
  const int quad = lane >> 4, l16 = lane & 15;
  const int tok0 = blockIdx.x * 32;

  f32x4 acc[2][5];
  #pragma unroll
  for (int rt = 0; rt < 2; ++rt)
    #pragma unroll
    for (int ctl = 0; ctl < 5; ++ctl) acc[rt][ctl] = (f32x4){0.f,0.f,0.f,0.f};

  // ---------------- scores GEMM: 8 chunks of BK=128, dbuf staging ----------
  // prologue: stage chunk 0 into xt0
  #pragma unroll
  for (int i = 0; i < 4; ++i) {
    int flat = i * 1024 + t * 4;
    int row = flat >> 7, col = flat & 127;
    float4 fv = *(const float4*)(x + (size_t)(tok0 + row) * 1024 + col);
    unsigned int pk0 = pack2bf(fv.x, fv.y), pk1 = pack2bf(fv.z, fv.w);
    *(unsigned long long*)&xt0[row * LDX + col] =
        (unsigned long long)pk0 | ((unsigned long long)pk1 << 32);
  }
  __syncthreads();

  for (int c = 0; c < 8; ++c) {
    ushort_t* cur = (c & 1) ? xt1 : xt0;
    ushort_t* nxt = (c & 1) ? xt0 : xt1;
    float4 fv[4];
    if (c < 7) {           // issue next chunk's global loads early
      #pragma unroll
      for (int i = 0; i < 4; ++i) {
        int flat = i * 1024 + t * 4;
        int row = flat >> 7, col = flat & 127;
        fv[i] = *(const float4*)(x + (size_t)(tok0 + row) * 1024 + (c + 1) * 128 + col);
      }
    }
    #pragma unroll
    for (int k4 = 0; k4 < 4; ++k4) {
      short8 a[2];
      #pragma unroll
      for (int rt = 0; rt < 2; ++rt)
        a[rt] = *(const short8*)&cur[(rt * 16 + l16) * LDX + k4 * 32 + quad * 8];
      #pragma unroll
      for (int ctl = 0; ctl < 5; ++ctl) {
        if (ctl == 4 && wid != 3) continue;     // wave-uniform branch
        const int ct = wid * 4 + ctl;
        short8 bfr = *(const short8*)&ws[KWQ_OFF +
            ((size_t)(c * 17 + ct) * 4 + k4) * 512 + (size_t)lane * 8];
        #pragma unroll
        for (int rt = 0; rt < 2; ++rt) acc[rt][ctl] = MFMA16(a[rt], bfr, acc[rt][ctl]);
      }
    }
    if (c < 7) {           // pack + write next buffer, single barrier per chunk
      #pragma unroll
      for (int i = 0; i < 4; ++i) {
        int flat = i * 1024 + t * 4;
        int row = flat >> 7, col = flat & 127;
        unsigned int pk0 = pack2bf(fv[i].x, fv[i].y), pk1 = pack2bf(fv[i].z, fv[i].w);
        *(unsigned long long*)&nxt[row * LDX + col] =
            (unsigned long long)pk0 | ((unsigned long long)pk1 << 32);
      }
      __syncthreads();
    }
  }

  // ---------------- cross-wave softmax --------------------------------------
  const float SC = 0.08838834764831845f * 1.44269504088896f;  // 1/sqrt(128) * log2e
  float Mx[2][4];
  #pragma unroll
  for (int rt = 0; rt < 2; ++rt)
    #pragma unroll
    for (int r = 0; r < 4; ++r) {
      float m = acc[rt][0][r];
      #pragma unroll
      for (int ctl = 1; ctl < 4; ++ctl) m = fmaxf(m, acc[rt][ctl][r]);
      #pragma unroll
      for (int msk = 1; msk < 16; msk <<= 1) m = fmaxf(m, __shfl_xor(m, msk, 64));
      Mx[rt][r] = m;
    }
  if (l16 == 0) {
    #pragma unroll
    for (int rt = 0; rt < 2; ++rt)
      #pragma unroll
      for (int r = 0; r < 4; ++r)
        pmax[(rt * 16 + quad * 4 + r) * 4 + wid] = Mx[rt][r];
  }
  __syncthreads();   // barrier: pmax complete (also closes last xt reads)
  float Mf[2][4];
  #pragma unroll
  for (int rt = 0; rt < 2; ++rt)
    #pragma unroll
    for (int r = 0; r < 4; ++r) {
      f32x4 pm = *(f32x4*)&pmax[(rt * 16 + quad * 4 + r) * 4];
      Mf[rt][r] = fmaxf(fmaxf(pm[0], pm[1]), fmaxf(pm[2], pm[3]));
    }
  float Sm[2][4];
  #pragma unroll
  for (int rt = 0; rt < 2; ++rt)
    #pragma unroll
    for (int r = 0; r < 4; ++r) Sm[rt][r] = 0.f;
  #pragma unroll
  for (int rt = 0; rt < 2; ++rt)
    #pragma unroll
    for (int ctl = 0; ctl < 4; ++ctl)
      #pragma unroll
      for (int r = 0; r < 4; ++r) {
        float e = exp2f((acc[rt][ctl][r] - Mf[rt][r]) * SC);
        acc[rt][ctl][r] = e;
        Sm[rt][r] += e;
      }
  #pragma unroll
  for (int rt = 0; rt < 2; ++rt)
    #pragma unroll
    for (int r = 0; r < 4; ++r) {
      #pragma unroll
      for (int msk = 1; msk < 16; msk <<= 1) Sm[rt][r] += __shfl_xor(Sm[rt][r], msk, 64);
    }
  if (l16 == 0) {
    #pragma unroll
    for (int rt = 0; rt < 2; ++rt)
      #pragma unroll
      for (int r = 0; r < 4; ++r)
        psum[(rt * 16 + quad * 4 + r) * 4 + wid] = Sm[rt][r];
    if (wid == 3) {
      float gb = gate_b[0];
      #pragma unroll
      for (int rt = 0; rt < 2; ++rt)
        #pragma unroll
        for (int r = 0; r < 4; ++r) {
          float lg = acc[rt][4][r] + gb;   // raw score, col 256 (l16==0)
          gate_lds[rt * 16 + quad * 4 + r] = 1.f / (1.f + __expf(-lg));
        }
    }
  }
  __syncthreads();   // barrier: psum + gate complete
  float scl[2][4];   // gate / sum  (gate folded into attn slab)
  #pragma unroll
  for (int rt = 0; rt < 2; ++rt)
    #pragma unroll
    for (int r = 0; r < 4; ++r) {
      f32x4 ps = *(f32x4*)&psum[(rt * 16 + quad * 4 + r) * 4];
      float g = gate_lds[rt * 16 + quad * 4 + r];
      scl[rt][r] = g / (ps[0] + ps[1] + ps[2] + ps[3]);
    }

  // attn*gate -> shared slab (each wave writes its ct columns)
  #pragma unroll
  for (int rt = 0; rt < 2; ++rt)
    #pragma unroll
    for (int ctl = 0; ctl < 4; ++ctl)
      #pragma unroll
      for (int r = 0; r < 4; ++r)
        slab[(rt * 16 + quad * 4 + r) * LDSLAB + (wid * 4 + ctl) * 16 + l16] =
            f2bf(acc[rt][ctl][r] * scl[rt][r]);
  __syncthreads();   // barrier: slab complete

  // ---------------- out GEMM: slab @ VWo, wave w owns cols [w*256, +256) ----
  short8 af[2][8];
  #pragma unroll
  for (int rt = 0; rt < 2; ++rt)
    #pragma unroll
    for (int k8 = 0; k8 < 8; ++k8)
      af[rt][k8] = *(const short8*)&slab[(rt * 16 + l16) * LDSLAB + k8 * 32 + quad * 8];

  const int n0 = wid * 256;
  for (int nt = 0; nt < 16; ++nt) {
    const int ctg = (n0 >> 4) + nt;
    short8 bf[8];
    #pragma unroll
    for (int k8 = 0; k8 < 8; ++k8)
      bf[k8] = *(const short8*)&ws[VWO_OFF + ((size_t)(ctg * 8 + k8) * 512) + (size_t)lane * 8];
    f32x4 oa[2];
    #pragma unroll
    for (int rt = 0; rt < 2; ++rt) oa[rt] = (f32x4){0.f,0.f,0.f,0.f};
    #pragma unroll
    for (int rt = 0; rt < 2; ++rt)
      #pragma unroll
      for (int k8 = 0; k8 < 8; ++k8)
        oa[rt] = MFMA16(af[rt][k8], bf[k8], oa[rt]);
    #pragma unroll
    for (int rt = 0; rt < 2; ++rt)
      #pragma unroll
      for (int r = 0; r < 4; ++r)
        __builtin_nontemporal_store(oa[rt][r],
            &out[(size_t)(tok0 + rt * 16 + quad * 4 + r) * 1024 + n0 + nt * 16 + l16]);
  }
}

// ---------------------------------------------------------------------------
extern "C" void kernel_launch(void* const* d_in, const int* in_sizes, int n_in,
                              void* d_out, int out_size, void* d_ws, size_t ws_size,
                              hipStream_t stream) {
  const float* x    = (const float*)d_in[0];
  const float* prim = (const float*)d_in[1];
  const float* Wq   = (const float*)d_in[2];
  const float* Wk   = (const float*)d_in[3];
  const float* Wv   = (const float*)d_in[4];
  const float* Wo   = (const float*)d_in[5];
  const float* gw   = (const float*)d_in[6];
  const float* gb   = (const float*)d_in[7];
  float* out = (float*)d_out;
  ushort_t* ws = (ushort_t*)d_ws;

  prep1_kernel<<<256, 256, 0, stream>>>(prim, Wk, Wv, ws);
  prep2_kernel<<<132, 256, 0, stream>>>(Wq, Wo, gw, ws);
  fused_kernel<<<1024, 256, 0, stream>>>(x, gb, ws, out);
}